// Round 5
// baseline (735.912 us; speedup 1.0000x reference)
//
#include <hip/hip_runtime.h>
#include <hip/hip_bf16.h>
#include <math.h>

// Dims from the reference
#define HH    8
#define DKK   64
#define GD    512
#define SD    3072
#define HID_  512
#define BB    16384

typedef unsigned short ushort_t;
typedef __attribute__((ext_vector_type(8))) short bf16x8;
typedef __attribute__((ext_vector_type(4))) float f32x4;

__device__ __forceinline__ float bf2f(ushort_t u) {
  union { unsigned int i; float f; } c; c.i = ((unsigned int)u) << 16; return c.f;
}
__device__ __forceinline__ ushort_t f2bf(float f) {
  union { float f; unsigned int i; } c; c.f = f;
  unsigned int x = c.i;
  return (ushort_t)((x + 0x7FFFu + ((x >> 16) & 1u)) >> 16);  // RNE
}
__device__ __forceinline__ unsigned int pk_bf16(float a, float b) {
  __hip_bfloat162 h = __float22bfloat162_rn(make_float2(a, b));
  union { __hip_bfloat162 h; unsigned int u; } c; c.h = h; return c.u;
}

__device__ __forceinline__ void async_cp16(const ushort_t* gsrc, ushort_t* ldst) {
  __builtin_amdgcn_global_load_lds(
      (const __attribute__((address_space(1))) unsigned int*)gsrc,
      (__attribute__((address_space(3))) unsigned int*)ldst, 16, 0, 0);
}

// tanh-form GELU: max |delta| vs exact erf-GELU ~3e-3, far under tolerance.
__device__ __forceinline__ float gelu_tanh(float x) {
  float y = 0.79788456080286535588f * (x + 0.044715f * x * x * x);
  float e = __expf(2.0f * y);
  float th = 1.0f - 2.0f / (e + 1.0f);
  return 0.5f * x * (1.0f + th);
}

// XCD-aware block swizzle: consecutive bids -> 8 XCDs; same-XCD successive
// blocks share an A row-panel -> A L2-resident.
// Requires NB, MB powers of two and NB*MB*KS % 8 == 0.
__device__ __forceinline__ void swz_coords(int& nb, int& mb, int& kz) {
  int NB = gridDim.x, MB = gridDim.y;
  int bid = blockIdx.x + NB * (blockIdx.y + MB * blockIdx.z);
  int xcd = bid & 7;
  int j = bid >> 3;
  nb = j & (NB - 1);
  int rest = j / NB;
  int mk = (rest << 3) | xcd;
  mb = mk & (MB - 1);
  kz = mk / MB;
}

// ---------------------------------------------------------------------------
// Register-direct GEMM: C[m][n] = sum_k A[m][k]*Bt[n][k] (+bias[n]).
// NO LDS, NO barriers, NO explicit waits. Each wave loads its own MFMA
// fragments straight from global (L2-served: B is 1-3 MB and panel-hot via
// XCD swizzle; A rows are re-read by only 2 waves) and free-runs. 16 waves/CU
// (4 blocks x 4 waves at <=128 VGPR) hide L2 latency; the compiler pipelines
// the straight-line loop with its own vmcnt counting.
// BM=BN=128, BK=32; 4 waves = 2(m) x 2(n), each 64x64 (4x4 16x16x32 MFMA).
// AF32: A is fp32 (converted to bf16 in-register at load time; identical RNE
// math to the previous LDS path). EPI: 0 = bias+bf16 store, 1 = gelu+bf16,
// 2 = raw fp32 partial to C + kz*M*N (split-K).
// ---------------------------------------------------------------------------
template <int EPI, int AF32>
__global__ __launch_bounds__(256, 4) void gemm_rd(
    const void* __restrict__ Av, const ushort_t* __restrict__ Bt,
    void* __restrict__ Cv, const float* __restrict__ bias,
    int M, int N, int Kfull, int Klen) {
  const int tid = threadIdx.x;
  const int wv = tid >> 6;
  const int lane = tid & 63;
  int nb, mb, kz;
  swz_coords(nb, mb, kz);
  const int m0 = mb * 128, n0 = nb * 128, kbeg = kz * Klen;
  const int wm = wv & 1, wn = wv >> 1;
  const int lr = lane & 15, quad = lane >> 4;

  f32x4 acc[4][4];
#pragma unroll
  for (int i = 0; i < 4; ++i)
#pragma unroll
    for (int j = 0; j < 4; ++j) acc[i][j] = (f32x4){0.f, 0.f, 0.f, 0.f};

  const size_t rstep = (size_t)16 * Kfull;   // 16 rows per fragment step
  // B fragment base: row n0 + wn*64 + lr, cols kbeg + quad*8 + k0
  const ushort_t* Bb = Bt + (size_t)(n0 + wn * 64 + lr) * Kfull + (kbeg + quad * 8);
  // A fragment base: row m0 + wm*64 + lr, cols kbeg + quad*8 + k0
  const float* Abf = (const float*)Av + (size_t)(m0 + wm * 64 + lr) * Kfull + (kbeg + quad * 8);
  const ushort_t* Abh = (const ushort_t*)Av + (size_t)(m0 + wm * 64 + lr) * Kfull + (kbeg + quad * 8);

  for (int k0 = 0; k0 < Klen; k0 += 32) {
    bf16x8 af[4], bfr[4];
#pragma unroll
    for (int j = 0; j < 4; ++j)
      bfr[j] = *(const bf16x8*)(Bb + (size_t)j * rstep + k0);
    if (AF32) {
#pragma unroll
      for (int i = 0; i < 4; ++i) {
        const float* pa = Abf + (size_t)i * rstep + k0;
        float4 fa = *(const float4*)pa;
        float4 fb = *(const float4*)(pa + 4);
        union { unsigned int u[4]; bf16x8 v; } c;
        c.u[0] = pk_bf16(fa.x, fa.y); c.u[1] = pk_bf16(fa.z, fa.w);
        c.u[2] = pk_bf16(fb.x, fb.y); c.u[3] = pk_bf16(fb.z, fb.w);
        af[i] = c.v;
      }
    } else {
#pragma unroll
      for (int i = 0; i < 4; ++i)
        af[i] = *(const bf16x8*)(Abh + (size_t)i * rstep + k0);
    }
#pragma unroll
    for (int i = 0; i < 4; ++i)
#pragma unroll
      for (int j = 0; j < 4; ++j)
        acc[i][j] = __builtin_amdgcn_mfma_f32_16x16x32_bf16(af[i], bfr[j], acc[i][j], 0, 0, 0);
  }

#pragma unroll
  for (int i = 0; i < 4; ++i) {
    const int mg = m0 + wm * 64 + i * 16 + quad * 4;
#pragma unroll
    for (int j = 0; j < 4; ++j) {
      const int ng = n0 + wn * 64 + j * 16 + lr;
      if (EPI == 2) {
        float* C = (float*)Cv + (size_t)kz * M * N;
#pragma unroll
        for (int r = 0; r < 4; ++r)
          C[(size_t)(mg + r) * N + ng] = acc[i][j][r];
      } else {
        ushort_t* C = (ushort_t*)Cv;
        const float bvv = bias ? bias[ng] : 0.0f;
#pragma unroll
        for (int r = 0; r < 4; ++r) {
          float v = acc[i][j][r] + bvv;
          if (EPI == 1) v = gelu_tanh(v);
          C[(size_t)(mg + r) * N + ng] = f2bf(v);
        }
      }
    }
  }
}

// ---------------------------------------------------------------------------
// LDS-staged GEMM, kept ONLY for the small folded-weight GEMM (M=512,N=3072,
// K=512, 96 blocks). Double-buffered, depth-1 prefetch, counted vmcnt.
// EPI 0 = bias + bf16 store. (R4-verified correct.)
// ---------------------------------------------------------------------------
template <int EPI, int SWZ>
__global__ __launch_bounds__(256) void gemm_bt(
    const ushort_t* __restrict__ A, const ushort_t* __restrict__ Bt,
    void* __restrict__ Cv, const float* __restrict__ bias,
    int M, int N, int Kfull, int Klen) {
  __shared__ __align__(16) ushort_t As[2][128 * 32];   // 8 KB x2
  __shared__ __align__(16) ushort_t Bs[2][128 * 32];   // 8 KB x2
  const int tid = threadIdx.x;
  const int wv = tid >> 6;
  const int lane = tid & 63;
  int nb, mb, kz;
  if (SWZ) swz_coords(nb, mb, kz);
  else { nb = blockIdx.x; mb = blockIdx.y; kz = blockIdx.z; }
  const int m0 = mb * 128, n0 = nb * 128, kbeg = kz * Klen;
  const int srow = lane >> 2;
  const int scol = (lane & 3) * 8;
  const int wm = wv & 1, wn = wv >> 1;
  const int lr = lane & 15, quad = lane >> 4;

  f32x4 acc[4][4];
#pragma unroll
  for (int i = 0; i < 4; ++i)
#pragma unroll
    for (int j = 0; j < 4; ++j) acc[i][j] = (f32x4){0.f, 0.f, 0.f, 0.f};

  const ushort_t* Ab = A + (size_t)m0 * Kfull + kbeg;
  const ushort_t* Bb = Bt + (size_t)n0 * Kfull + kbeg;

  auto stage = [&](int k0, int b) {      // 4 vm insts per wave (2 A + 2 B)
#pragma unroll
    for (int i = 0; i < 2; ++i) {
      const int chunk = i * 4 + wv;      // wave-uniform
      const int row = chunk * 16 + srow;
      async_cp16(Ab + (size_t)row * Kfull + (k0 + scol), &As[b][chunk * 512]);
      async_cp16(Bb + (size_t)row * Kfull + (k0 + scol), &Bs[b][chunk * 512]);
    }
  };

  const int nt = Klen >> 5;
  stage(0, 0);
  int buf = 0;
  for (int t = 0; t < nt; ++t, buf ^= 1) {
    if (t + 1 < nt) {
      stage((t + 1) << 5, buf ^ 1);      // prefetch next tile first
      asm volatile("s_waitcnt vmcnt(4)" ::: "memory");  // wait tile t only
    } else {
      asm volatile("s_waitcnt vmcnt(0)" ::: "memory");  // epilogue drain
    }
    __builtin_amdgcn_s_barrier();        // buf published for ALL waves
    __builtin_amdgcn_sched_barrier(0);
    bf16x8 af[4], bfr[4];
#pragma unroll
    for (int i = 0; i < 4; ++i)
      af[i] = *(const bf16x8*)&As[buf][(wm * 64 + i * 16 + lr) * 32 + quad * 8];
#pragma unroll
    for (int j = 0; j < 4; ++j)
      bfr[j] = *(const bf16x8*)&Bs[buf][(wn * 64 + j * 16 + lr) * 32 + quad * 8];
#pragma unroll
    for (int i = 0; i < 4; ++i)
#pragma unroll
      for (int j = 0; j < 4; ++j)
        acc[i][j] = __builtin_amdgcn_mfma_f32_16x16x32_bf16(af[i], bfr[j], acc[i][j], 0, 0, 0);
    __builtin_amdgcn_sched_barrier(0);
    __builtin_amdgcn_s_barrier();        // all reads of buf consumed
  }

#pragma unroll
  for (int i = 0; i < 4; ++i) {
    const int mg = m0 + wm * 64 + i * 16 + quad * 4;
#pragma unroll
    for (int j = 0; j < 4; ++j) {
      const int ng = n0 + wn * 64 + j * 16 + lr;
      if (EPI == 2) {
        float* C = (float*)Cv + (size_t)kz * M * N;
#pragma unroll
        for (int r = 0; r < 4; ++r)
          C[(size_t)(mg + r) * N + ng] = acc[i][j][r];
      } else {
        ushort_t* C = (ushort_t*)Cv;
        const float bvv = bias ? bias[ng] : 0.0f;
#pragma unroll
        for (int r = 0; r < 4; ++r) {
          float v = acc[i][j][r] + bvv;
          if (EPI == 1) v = gelu_tanh(v);
          C[(size_t)(mg + r) * N + ng] = f2bf(v);
        }
      }
    }
  }
}

// Wvp[s][c] = Wv[h=c>>6][s][d=c&63], fp32 -> bf16. 8 outputs/thread (same h).
__global__ __launch_bounds__(256) void permute_wv(const float* __restrict__ Wv,
                                                  ushort_t* __restrict__ Wvp) {
  const int idx = (blockIdx.x * 256 + threadIdx.x) * 8;
  const int s = idx >> 9;
  const int c = idx & 511;
  const float* src = Wv + (size_t)(c >> 6) * (SD * DKK) + (size_t)s * DKK + (c & 63);
  float4 a = *(const float4*)src;
  float4 b = *(const float4*)(src + 4);
  unsigned int p[4];
  p[0] = pk_bf16(a.x, a.y); p[1] = pk_bf16(a.z, a.w);
  p[2] = pk_bf16(b.x, b.y); p[3] = pk_bf16(b.z, b.w);
  *(uint4*)(Wvp + idx) = *(const uint4*)p;
}

// Three weight transposes in one launch (z selects). dst[C][R] = src[R][C]^T.
__global__ __launch_bounds__(256) void transpose3(
    const float* __restrict__ s0, ushort_t* __restrict__ d0,
    const float* __restrict__ s1, ushort_t* __restrict__ d1,
    const float* __restrict__ s2, ushort_t* __restrict__ d2) {
  __shared__ ushort_t tile[32][33];
  const int z = blockIdx.z;
  const float* src = (z == 0) ? s0 : (z == 1) ? s1 : s2;
  ushort_t* dst = (z == 0) ? d0 : (z == 1) ? d1 : d2;
  const int R = (z == 2) ? 1024 : 512;
  const int C = (z == 1) ? 1024 : 512;
  const int bx = blockIdx.x * 32;
  const int by = blockIdx.y * 32;
  if (bx >= C || by >= R) return;
  const int tx = threadIdx.x, ty = threadIdx.y;
#pragma unroll
  for (int i = 0; i < 32; i += 8)
    tile[ty + i][tx] = f2bf(src[(size_t)(by + ty + i) * C + (bx + tx)]);
  __syncthreads();
#pragma unroll
  for (int i = 0; i < 32; i += 8)
    dst[(size_t)(bx + ty + i) * R + (by + tx)] = tile[tx][ty + i];
}

// c0[j] = sum_c bv[c]*Wo[c][j] + bo[j].
__global__ __launch_bounds__(256) void c0_kernel(const float* __restrict__ bv,
                                                 const float* __restrict__ Wo,
                                                 const float* __restrict__ bo,
                                                 float* __restrict__ c0) {
  __shared__ float red[8][32];
  const int jl = threadIdx.x & 31;
  const int chunk = threadIdx.x >> 5;
  const int j = blockIdx.x * 32 + jl;
  const int cbase = chunk * 64;
  float s = 0.f;
#pragma unroll 8
  for (int c = 0; c < 64; ++c) s += bv[cbase + c] * Wo[(size_t)(cbase + c) * 512 + j];
  red[chunk][jl] = s;
  __syncthreads();
  if (chunk == 0) {
    float t = bo[j];
#pragma unroll
    for (int q = 0; q < 8; ++q) t += red[q][jl];
    c0[j] = t;
  }
}

// out = LN(p0 + p1 + cb + res) * g + b over rows of 512; one wave per row.
// p0,p1 fp32 split-K partials; cb fp32 column bias; res fp32 or bf16.
template <int RES_F32, int OUT_F32>
__global__ __launch_bounds__(256) void ln_fused(const float* __restrict__ p0,
                                                const float* __restrict__ p1,
                                                const float* __restrict__ cb,
                                                const void* __restrict__ res_,
                                                const float* __restrict__ g,
                                                const float* __restrict__ b,
                                                void* __restrict__ out_) {
  const int row = blockIdx.x * 4 + (threadIdx.x >> 6);
  const int lane = threadIdx.x & 63;
  const size_t base = (size_t)row * 512 + lane * 8;
  const int col = lane * 8;
  float4 a0 = *(const float4*)(p0 + base);
  float4 a1 = *(const float4*)(p0 + base + 4);
  float4 c0v = *(const float4*)(p1 + base);
  float4 c1v = *(const float4*)(p1 + base + 4);
  float4 d0 = *(const float4*)(cb + col);
  float4 d1 = *(const float4*)(cb + col + 4);
  float t[8];
  t[0] = a0.x + c0v.x + d0.x; t[1] = a0.y + c0v.y + d0.y;
  t[2] = a0.z + c0v.z + d0.z; t[3] = a0.w + c0v.w + d0.w;
  t[4] = a1.x + c1v.x + d1.x; t[5] = a1.y + c1v.y + d1.y;
  t[6] = a1.z + c1v.z + d1.z; t[7] = a1.w + c1v.w + d1.w;
  float r[8];
  if (RES_F32) {
    const float* res = (const float*)res_;
    float4 e0 = *(const float4*)(res + base);
    float4 e1 = *(const float4*)(res + base + 4);
    r[0] = e0.x; r[1] = e0.y; r[2] = e0.z; r[3] = e0.w;
    r[4] = e1.x; r[5] = e1.y; r[6] = e1.z; r[7] = e1.w;
  } else {
    const ushort_t* res = (const ushort_t*)res_;
    uint4 rv = *(const uint4*)(res + base);
    const ushort_t* rp = (const ushort_t*)&rv;
#pragma unroll
    for (int k = 0; k < 8; ++k) r[k] = bf2f(rp[k]);
  }
  float x[8];
  float s = 0.f, sq = 0.f;
#pragma unroll
  for (int k = 0; k < 8; ++k) {
    float v = t[k] + r[k];
    x[k] = v; s += v; sq += v * v;
  }
#pragma unroll
  for (int off = 32; off > 0; off >>= 1) {
    s += __shfl_xor(s, off);
    sq += __shfl_xor(sq, off);
  }
  const float mean = s * (1.0f / 512.0f);
  const float var = sq * (1.0f / 512.0f) - mean * mean;
  const float rstd = rsqrtf(var + 1e-5f);
  float4 gv0 = *(const float4*)(g + col);
  float4 gv1 = *(const float4*)(g + col + 4);
  float4 bv0 = *(const float4*)(b + col);
  float4 bv1 = *(const float4*)(b + col + 4);
  const float gg[8] = {gv0.x, gv0.y, gv0.z, gv0.w, gv1.x, gv1.y, gv1.z, gv1.w};
  const float bb[8] = {bv0.x, bv0.y, bv0.z, bv0.w, bv1.x, bv1.y, bv1.z, bv1.w};
  float y[8];
#pragma unroll
  for (int k = 0; k < 8; ++k) y[k] = (x[k] - mean) * rstd * gg[k] + bb[k];
  if (OUT_F32) {
    float* out = (float*)out_;
    *(float4*)(out + base) = make_float4(y[0], y[1], y[2], y[3]);
    *(float4*)(out + base + 4) = make_float4(y[4], y[5], y[6], y[7]);
  } else {
    ushort_t* out = (ushort_t*)out_;
    uint4 ov; ushort_t* op = (ushort_t*)&ov;
#pragma unroll
    for (int k = 0; k < 8; ++k) op[k] = f2bf(y[k]);
    *(uint4*)(out + base) = ov;
  }
}

extern "C" void kernel_launch(void* const* d_in, const int* in_sizes, int n_in,
                              void* d_out, int out_size, void* d_ws, size_t ws_size,
                              hipStream_t stream) {
  const float* h_g  = (const float*)d_in[0];
  const float* h_s  = (const float*)d_in[1];
  // d_in[2..5] = Wq,bq,Wk,bk — dead code (softmax over 1 key == 1, attn == V)
  const float* Wv   = (const float*)d_in[6];
  const float* bv   = (const float*)d_in[7];
  const float* Wo   = (const float*)d_in[8];
  const float* bo   = (const float*)d_in[9];
  const float* ln1g = (const float*)d_in[10];
  const float* ln1b = (const float*)d_in[11];
  const float* W1   = (const float*)d_in[12];
  const float* b1   = (const float*)d_in[13];
  const float* W2   = (const float*)d_in[14];
  const float* b2   = (const float*)d_in[15];
  const float* ln2g = (const float*)d_in[16];
  const float* ln2b = (const float*)d_in[17];

  char* ws = (char*)d_ws;
  ushort_t* WoT = (ushort_t*)(ws + 0);            // 512x512 bf16   (0.5 MiB)
  ushort_t* W1T = (ushort_t*)(ws + 524288);       // 1024x512 bf16  (1 MiB)
  ushort_t* W2T = (ushort_t*)(ws + 1572864);      // 512x1024 bf16  (1 MiB)
  ushort_t* Wvp = (ushort_t*)(ws + 2621440);      // 3072x512 bf16  (3 MiB)
  ushort_t* WcT = (ushort_t*)(ws + 5767168);      // 512x3072 bf16  (3 MiB)
  float*    c0f = (float*)(ws + 8912896);         // 512 f32
  float*    p0  = (float*)(ws + 16777216);        // 16384x512 f32  (32 MiB)
  float*    p1  = (float*)(ws + 50331648);        // 16384x512 f32  (32 MiB)
  ushort_t* x   = (ushort_t*)(ws + 83886080);     // 16384x512 bf16 (16 MiB)
  ushort_t* u   = (ushort_t*)(ws + 100663296);    // 16384x1024 bf16 (32 MiB)
  // q0/q1 (W2 partials) alias p0/p1 — p* are dead after LN1.
  float*    q0  = p0;
  float*    q1  = p1;
  (void)in_sizes; (void)n_in; (void)out_size; (void)ws_size;

  // --- prep (tiny) ---
  hipLaunchKernelGGL(permute_wv, dim3(768), dim3(256), 0, stream, Wv, Wvp);
  hipLaunchKernelGGL(transpose3, dim3(32, 32, 3), dim3(32, 8), 0, stream,
                     Wo, WoT, W1, W1T, W2, W2T);
  hipLaunchKernelGGL(c0_kernel, dim3(16), dim3(256), 0, stream, bv, Wo, bo, c0f);

  // --- folded weight: WcT[j][s] = sum_c WoT[j][c] * Wvp[s][c]  (M=512,N=3072,K=512)
  hipLaunchKernelGGL((gemm_bt<0, 0>), dim3(24, 4, 1), dim3(256), 0, stream,
                     WoT, Wvp, (void*)WcT, (const float*)nullptr, 512, 3072, 512, 512);
  // --- p0,p1 = split-K partials of h_s @ Wc   (M=16384,N=512,K=3072, ks=2)
  hipLaunchKernelGGL((gemm_rd<2, 1>), dim3(4, 128, 2), dim3(256), 0, stream,
                     (const void*)h_s, WcT, (void*)p0, (const float*)nullptr,
                     BB, 512, 3072, 1536);
  // --- x = LN1(p0 + p1 + c0 + h_g)   (res fp32, out bf16)
  hipLaunchKernelGGL((ln_fused<1, 0>), dim3(4096), dim3(256), 0, stream,
                     p0, p1, c0f, (const void*)h_g, ln1g, ln1b, (void*)x);
  // --- u = gelu(x @ W1 + b1)   (M=16384,N=1024,K=512)
  hipLaunchKernelGGL((gemm_rd<1, 0>), dim3(8, 128, 1), dim3(256), 0, stream,
                     (const void*)x, W1T, (void*)u, b1, BB, 1024, 512, 512);
  // --- q0,q1 = split-K partials of u @ W2   (M=16384,N=512,K=1024, ks=2)
  hipLaunchKernelGGL((gemm_rd<2, 0>), dim3(4, 128, 2), dim3(256), 0, stream,
                     (const void*)u, W2T, (void*)q0, (const float*)nullptr,
                     BB, 512, 1024, 512);
  // --- out = LN2(q0 + q1 + b2 + x)   (res bf16, out fp32)
  hipLaunchKernelGGL((ln_fused<0, 1>), dim3(4096), dim3(256), 0, stream,
                     q0, q1, b2, (const void*)x, ln2g, ln2b, d_out);
}

// Round 6
// 505.008 us; speedup vs baseline: 1.4572x; 1.4572x over previous
//
#include <hip/hip_runtime.h>
#include <hip/hip_bf16.h>
#include <math.h>

// Dims from the reference
#define HH    8
#define DKK   64
#define GD    512
#define SD    3072
#define HID_  512
#define BB    16384

typedef unsigned short ushort_t;
typedef __attribute__((ext_vector_type(8))) short bf16x8;
typedef __attribute__((ext_vector_type(4))) float f32x4;

__device__ __forceinline__ float bf2f(ushort_t u) {
  union { unsigned int i; float f; } c; c.i = ((unsigned int)u) << 16; return c.f;
}
__device__ __forceinline__ ushort_t f2bf(float f) {
  union { float f; unsigned int i; } c; c.f = f;
  unsigned int x = c.i;
  return (ushort_t)((x + 0x7FFFu + ((x >> 16) & 1u)) >> 16);  // RNE
}
__device__ __forceinline__ unsigned int pk_bf16(float a, float b) {
  __hip_bfloat162 h = __float22bfloat162_rn(make_float2(a, b));
  union { __hip_bfloat162 h; unsigned int u; } c; c.h = h; return c.u;
}

__device__ __forceinline__ void async_cp16(const ushort_t* gsrc, ushort_t* ldst) {
  __builtin_amdgcn_global_load_lds(
      (const __attribute__((address_space(1))) unsigned int*)gsrc,
      (__attribute__((address_space(3))) unsigned int*)ldst, 16, 0, 0);
}
__device__ __forceinline__ void async_cp16f(const float* gsrc, float* ldst) {
  __builtin_amdgcn_global_load_lds(
      (const __attribute__((address_space(1))) unsigned int*)gsrc,
      (__attribute__((address_space(3))) unsigned int*)ldst, 16, 0, 0);
}

// tanh-form GELU: max |delta| vs exact erf-GELU ~3e-3, far under tolerance.
__device__ __forceinline__ float gelu_tanh(float x) {
  float y = 0.79788456080286535588f * (x + 0.044715f * x * x * x);
  float e = __expf(2.0f * y);
  float th = 1.0f - 2.0f / (e + 1.0f);
  return 0.5f * x * (1.0f + th);
}

// XCD-aware block swizzle (for gemm_bt). Requires NB, MB pow2, NB*MB*KS%8==0.
__device__ __forceinline__ void swz_coords(int& nb, int& mb, int& kz) {
  int NB = gridDim.x, MB = gridDim.y;
  int bid = blockIdx.x + NB * (blockIdx.y + MB * blockIdx.z);
  int xcd = bid & 7;
  int j = bid >> 3;
  nb = j & (NB - 1);
  int rest = j / NB;
  int mk = (rest << 3) | xcd;
  mb = mk & (MB - 1);
  kz = mk / MB;
}

// ---------------------------------------------------------------------------
// R0-proven serial LDS GEMM (best measured for the bf16 GEMMs).
// C[m][n] = sum_k A[m][k]*Bt[n][k] (+bias[n]); BM=BN=128, BK=32, 24KB LDS.
// EPI: 0 = bias+bf16 store, 1 = gelu+bf16, 2 = fp32 partial (split-K).
// ---------------------------------------------------------------------------
template <int EPI, int SWZ>
__global__ __launch_bounds__(256) void gemm_bt(
    const ushort_t* __restrict__ A, const ushort_t* __restrict__ Bt,
    void* __restrict__ Cv, const float* __restrict__ bias,
    int M, int N, int Kfull, int Klen) {
  __shared__ __align__(16) ushort_t As[128 * 32];
  __shared__ __align__(16) ushort_t Bs[128 * 32];
  const int tid = threadIdx.x;
  const int wv = tid >> 6;
  const int lane = tid & 63;
  int nb, mb, kz;
  if (SWZ) swz_coords(nb, mb, kz);
  else { nb = blockIdx.x; mb = blockIdx.y; kz = blockIdx.z; }
  const int m0 = mb * 128, n0 = nb * 128, kbeg = kz * Klen;
  const int srow = lane >> 2;
  const int scol = (lane & 3) * 8;
  const int wm = wv & 1, wn = wv >> 1;
  const int lr = lane & 15, quad = lane >> 4;

  f32x4 acc[4][4];
#pragma unroll
  for (int i = 0; i < 4; ++i)
#pragma unroll
    for (int j = 0; j < 4; ++j) acc[i][j] = (f32x4){0.f, 0.f, 0.f, 0.f};

  const ushort_t* Ab = A + (size_t)m0 * Kfull + kbeg;
  const ushort_t* Bb = Bt + (size_t)n0 * Kfull + kbeg;

  for (int k0 = 0; k0 < Klen; k0 += 32) {
    __syncthreads();
#pragma unroll
    for (int i = 0; i < 2; ++i) {
      const int chunk = i * 4 + wv;          // wave-uniform
      const int row = chunk * 16 + srow;
      async_cp16(Ab + (size_t)row * Kfull + (k0 + scol), As + chunk * 512);
      async_cp16(Bb + (size_t)row * Kfull + (k0 + scol), Bs + chunk * 512);
    }
    __syncthreads();
    bf16x8 af[4], bfr[4];
#pragma unroll
    for (int i = 0; i < 4; ++i)
      af[i] = *(const bf16x8*)&As[(wm * 64 + i * 16 + lr) * 32 + quad * 8];
#pragma unroll
    for (int j = 0; j < 4; ++j)
      bfr[j] = *(const bf16x8*)&Bs[(wn * 64 + j * 16 + lr) * 32 + quad * 8];
#pragma unroll
    for (int i = 0; i < 4; ++i)
#pragma unroll
      for (int j = 0; j < 4; ++j)
        acc[i][j] = __builtin_amdgcn_mfma_f32_16x16x32_bf16(af[i], bfr[j], acc[i][j], 0, 0, 0);
  }

#pragma unroll
  for (int i = 0; i < 4; ++i) {
    const int mg = m0 + wm * 64 + i * 16 + quad * 4;
#pragma unroll
    for (int j = 0; j < 4; ++j) {
      const int ng = n0 + wn * 64 + j * 16 + lr;
      if (EPI == 2) {
        float* C = (float*)Cv + (size_t)kz * M * N;
#pragma unroll
        for (int r = 0; r < 4; ++r)
          C[(size_t)(mg + r) * N + ng] = acc[i][j][r];
      } else {
        ushort_t* C = (ushort_t*)Cv;
        const float bvv = bias ? bias[ng] : 0.0f;
#pragma unroll
        for (int r = 0; r < 4; ++r) {
          float v = acc[i][j][r] + bvv;
          if (EPI == 1) v = gelu_tanh(v);
          C[(size_t)(mg + r) * N + ng] = f2bf(v);
        }
      }
    }
  }
}

// ---------------------------------------------------------------------------
// 8-phase big GEMM (T2+T3+T4+T5): C = A(fp32,[M][K]) @ Bt(bf16,[N][K])^T,
// fp32 out. BM=128, BN=256, BK=64, 512 thr (8 waves = 2M x 4N, 64x64 each).
// LDS 128KB dynamic: Af[2][128][64] fp32 (XOR-16-granule swz) +
// Bs[2][256][64] bf16 (XOR-8-granule swz). 1 block/CU, grid (2,128), ks=1.
// Per K-tile t: 4 phases {ds_read || 2 stage-issues || bar || setprio+8 MFMA
// || lgkm0+bar}; staging runs 1.5 tiles ahead: B(t+1) in ph0-1 (buf^1),
// A(t+2) in ph2-3 (buf, safe after ph1's close). Boundary s_waitcnt
// vmcnt(4) leaves A(t+2) in flight (never drains to 0 mid-loop).
// FIFO audit (steady): outstanding at tile end = A(t+1)4 + B(t+1)4 +
// A(t+2)4 = 12 -> vmcnt(4) retires exactly {A,B}(t+1). Prologue stages
// A(t0),B(t0),A(t1) then vmcnt(4). Epilogue: t>=nt-2 waits vmcnt(0).
// ---------------------------------------------------------------------------
__global__ __launch_bounds__(512, 2) void gemm8_a32(
    const float* __restrict__ A, const ushort_t* __restrict__ Bt,
    float* __restrict__ C, int M, int N, int K) {
  extern __shared__ char smem[];
  float* Af = (float*)smem;                         // 2 x 8192 floats (64KB)
  ushort_t* Bsm = (ushort_t*)(smem + 65536);        // 2 x 16384 ushorts (64KB)
  const int tid = threadIdx.x;
  const int wv = tid >> 6;
  const int lane = tid & 63;
  const int lr = lane & 15, quad = lane >> 4;
  const int wm = wv >> 2, wn = wv & 3;
  // block swizzle: nb-siblings of one mb share an XCD (A-panel L2 reuse)
  const int bid = blockIdx.x + (int)gridDim.x * blockIdx.y;   // 0..255
  const int xcd = bid & 7;
  const int jj = bid >> 3;                                    // 0..31
  const int nb = jj & 1;
  const int mb = xcd * 16 + (jj >> 1);                        // 0..127
  const int m0 = mb * 128, n0 = nb * 256;

  // --- staging address precompute (wave-uniform LDS dest base; per-lane src)
  // A: inst i covers chunk c=i*8+wv (4 rows of 256B). lane l -> row c*4+(l>>4),
  //    slot l&15 holds logical granule (l&15)^(r&7), r&7 = (wv&1)*4+(l>>4).
  const int a_r0 = wv * 4 + (lane >> 4);
  const int a_g = (lane & 15) ^ ((wv & 1) * 4 + (lane >> 4));
  const float* Asrc = A + (size_t)(m0 + a_r0) * K + a_g * 4;
  // B: inst i covers chunk c=i*8+wv (8 rows of 128B). lane l -> row c*8+(l>>3),
  //    slot l&7 holds logical granule (l&7)^(l>>3).
  const int b_r0 = wv * 8 + (lane >> 3);
  const int b_g = (lane & 7) ^ (lane >> 3);
  const ushort_t* Bsrc = Bt + (size_t)(n0 + b_r0) * K + b_g * 8;

  f32x4 acc[4][4];
#pragma unroll
  for (int i = 0; i < 4; ++i)
#pragma unroll
    for (int j = 0; j < 4; ++j) acc[i][j] = (f32x4){0.f, 0.f, 0.f, 0.f};

  // stage two A-insts {i0,i0+1} of K-window k0 into buffer b
  auto stageA2 = [&](int k0, int b, int i0) {
#pragma unroll
    for (int i = 0; i < 2; ++i) {
      const int ii = i0 + i;
      async_cp16f(Asrc + (size_t)(ii * 32) * K + k0,
                  Af + b * 8192 + ii * 2048 + wv * 256);   // wave-uniform dest
    }
  };
  auto stageB2 = [&](int k0, int b, int i0) {
#pragma unroll
    for (int i = 0; i < 2; ++i) {
      const int ii = i0 + i;
      async_cp16(Bsrc + (size_t)(ii * 64) * K + k0,
                 Bsm + b * 16384 + ii * 4096 + wv * 512);  // wave-uniform dest
    }
  };

  // --- prologue: A(t0), B(t0), A(t1); wait A0+B0 done (8 oldest), A1 flies.
  stageA2(0, 0, 0); stageA2(0, 0, 2);
  stageB2(0, 0, 0); stageB2(0, 0, 2);
  stageA2(64, 1, 0); stageA2(64, 1, 2);
  asm volatile("s_waitcnt vmcnt(4)" ::: "memory");
  __builtin_amdgcn_sched_barrier(0);
  __builtin_amdgcn_s_barrier();

  const int nt = K >> 6;                 // 48
  for (int t = 0; t < nt; ++t) {
    const int b = t & 1;
    const int kB = (t + 1) << 6;
    const int kA = (t + 2) << 6;
    const bool hasB = (t + 1 < nt);
    const bool hasA = (t + 2 < nt);
    const float* Ab = Af + b * 8192;
    const ushort_t* Bb = Bsm + b * 16384;

    // ---- PH0: read all B frags + A mfrag0,1; issue B(t+1) insts 0,1
    bf16x8 bfr[4][2];
#pragma unroll
    for (int jf = 0; jf < 4; ++jf) {
      const int r = wn * 64 + jf * 16 + lr;
#pragma unroll
      for (int kk = 0; kk < 2; ++kk) {
        const int pg = (kk * 4 + quad) ^ (lr & 7);
        bfr[jf][kk] = *(const bf16x8*)(Bb + r * 64 + pg * 8);
      }
    }
    bf16x8 af0[2], af1[2], af2[2], af3[2];
    {
      const float* base0 = Ab + (wm * 64 + 0 * 16 + lr) * 64;
      const float* base1 = Ab + (wm * 64 + 1 * 16 + lr) * 64;
#pragma unroll
      for (int kk = 0; kk < 2; ++kk) {
        const int g0 = (kk * 8 + 2 * quad) ^ (lr & 7);
        const int g1 = (kk * 8 + 2 * quad + 1) ^ (lr & 7);
        float4 fa = *(const float4*)(base0 + g0 * 4);
        float4 fb = *(const float4*)(base0 + g1 * 4);
        union { unsigned int u[4]; bf16x8 v; } c0;
        c0.u[0] = pk_bf16(fa.x, fa.y); c0.u[1] = pk_bf16(fa.z, fa.w);
        c0.u[2] = pk_bf16(fb.x, fb.y); c0.u[3] = pk_bf16(fb.z, fb.w);
        af0[kk] = c0.v;
        float4 ga = *(const float4*)(base1 + g0 * 4);
        float4 gb = *(const float4*)(base1 + g1 * 4);
        union { unsigned int u[4]; bf16x8 v; } c1;
        c1.u[0] = pk_bf16(ga.x, ga.y); c1.u[1] = pk_bf16(ga.z, ga.w);
        c1.u[2] = pk_bf16(gb.x, gb.y); c1.u[3] = pk_bf16(gb.z, gb.w);
        af1[kk] = c1.v;
      }
    }
    if (hasB) stageB2(kB, b ^ 1, 0);
    __builtin_amdgcn_s_barrier();
    __builtin_amdgcn_s_setprio(1);
#pragma unroll
    for (int jf = 0; jf < 4; ++jf) {
      acc[0][jf] = __builtin_amdgcn_mfma_f32_16x16x32_bf16(af0[0], bfr[jf][0], acc[0][jf], 0, 0, 0);
      acc[0][jf] = __builtin_amdgcn_mfma_f32_16x16x32_bf16(af0[1], bfr[jf][1], acc[0][jf], 0, 0, 0);
    }
    __builtin_amdgcn_s_setprio(0);
    asm volatile("s_waitcnt lgkmcnt(0)" ::: "memory");
    __builtin_amdgcn_sched_barrier(0);
    __builtin_amdgcn_s_barrier();

    // ---- PH1: read A mfrag2,3; issue B(t+1) insts 2,3
    {
      const float* base2 = Ab + (wm * 64 + 2 * 16 + lr) * 64;
      const float* base3 = Ab + (wm * 64 + 3 * 16 + lr) * 64;
#pragma unroll
      for (int kk = 0; kk < 2; ++kk) {
        const int g0 = (kk * 8 + 2 * quad) ^ (lr & 7);
        const int g1 = (kk * 8 + 2 * quad + 1) ^ (lr & 7);
        float4 fa = *(const float4*)(base2 + g0 * 4);
        float4 fb = *(const float4*)(base2 + g1 * 4);
        union { unsigned int u[4]; bf16x8 v; } c2;
        c2.u[0] = pk_bf16(fa.x, fa.y); c2.u[1] = pk_bf16(fa.z, fa.w);
        c2.u[2] = pk_bf16(fb.x, fb.y); c2.u[3] = pk_bf16(fb.z, fb.w);
        af2[kk] = c2.v;
        float4 ga = *(const float4*)(base3 + g0 * 4);
        float4 gb = *(const float4*)(base3 + g1 * 4);
        union { unsigned int u[4]; bf16x8 v; } c3;
        c3.u[0] = pk_bf16(ga.x, ga.y); c3.u[1] = pk_bf16(ga.z, ga.w);
        c3.u[2] = pk_bf16(gb.x, gb.y); c3.u[3] = pk_bf16(gb.z, gb.w);
        af3[kk] = c3.v;
      }
    }
    if (hasB) stageB2(kB, b ^ 1, 2);
    __builtin_amdgcn_s_barrier();
    __builtin_amdgcn_s_setprio(1);
#pragma unroll
    for (int jf = 0; jf < 4; ++jf) {
      acc[1][jf] = __builtin_amdgcn_mfma_f32_16x16x32_bf16(af1[0], bfr[jf][0], acc[1][jf], 0, 0, 0);
      acc[1][jf] = __builtin_amdgcn_mfma_f32_16x16x32_bf16(af1[1], bfr[jf][1], acc[1][jf], 0, 0, 0);
    }
    __builtin_amdgcn_s_setprio(0);
    asm volatile("s_waitcnt lgkmcnt(0)" ::: "memory");   // all reads of buf b done
    __builtin_amdgcn_sched_barrier(0);
    __builtin_amdgcn_s_barrier();

    // ---- PH2: issue A(t+2) insts 0,1 (into buf b, safe after PH1 close)
    if (hasA) stageA2(kA, b, 0);
    __builtin_amdgcn_s_barrier();
    __builtin_amdgcn_s_setprio(1);
#pragma unroll
    for (int jf = 0; jf < 4; ++jf) {
      acc[2][jf] = __builtin_amdgcn_mfma_f32_16x16x32_bf16(af2[0], bfr[jf][0], acc[2][jf], 0, 0, 0);
      acc[2][jf] = __builtin_amdgcn_mfma_f32_16x16x32_bf16(af2[1], bfr[jf][1], acc[2][jf], 0, 0, 0);
    }
    __builtin_amdgcn_s_setprio(0);
    __builtin_amdgcn_sched_barrier(0);
    __builtin_amdgcn_s_barrier();

    // ---- PH3: issue A(t+2) insts 2,3; MFMA; boundary counted wait
    if (hasA) stageA2(kA, b, 2);
    __builtin_amdgcn_s_barrier();
    __builtin_amdgcn_s_setprio(1);
#pragma unroll
    for (int jf = 0; jf < 4; ++jf) {
      acc[3][jf] = __builtin_amdgcn_mfma_f32_16x16x32_bf16(af3[0], bfr[jf][0], acc[3][jf], 0, 0, 0);
      acc[3][jf] = __builtin_amdgcn_mfma_f32_16x16x32_bf16(af3[1], bfr[jf][1], acc[3][jf], 0, 0, 0);
    }
    __builtin_amdgcn_s_setprio(0);
    if (t < nt - 2) {
      asm volatile("s_waitcnt vmcnt(4)" ::: "memory");   // retire {A,B}(t+1)
    } else {
      asm volatile("s_waitcnt vmcnt(0)" ::: "memory");   // epilogue drain
    }
    __builtin_amdgcn_sched_barrier(0);
    __builtin_amdgcn_s_barrier();
  }

#pragma unroll
  for (int m = 0; m < 4; ++m) {
    const int mg = m0 + wm * 64 + m * 16 + quad * 4;
#pragma unroll
    for (int jf = 0; jf < 4; ++jf) {
      const int ng = n0 + wn * 64 + jf * 16 + lr;
#pragma unroll
      for (int r = 0; r < 4; ++r)
        C[(size_t)(mg + r) * N + ng] = acc[m][jf][r];
    }
  }
}

// Wvp[s][c] = Wv[h=c>>6][s][d=c&63], fp32 -> bf16. 8 outputs/thread (same h).
__global__ __launch_bounds__(256) void permute_wv(const float* __restrict__ Wv,
                                                  ushort_t* __restrict__ Wvp) {
  const int idx = (blockIdx.x * 256 + threadIdx.x) * 8;
  const int s = idx >> 9;
  const int c = idx & 511;
  const float* src = Wv + (size_t)(c >> 6) * (SD * DKK) + (size_t)s * DKK + (c & 63);
  float4 a = *(const float4*)src;
  float4 b = *(const float4*)(src + 4);
  unsigned int p[4];
  p[0] = pk_bf16(a.x, a.y); p[1] = pk_bf16(a.z, a.w);
  p[2] = pk_bf16(b.x, b.y); p[3] = pk_bf16(b.z, b.w);
  *(uint4*)(Wvp + idx) = *(const uint4*)p;
}

// Three weight transposes in one launch (z selects). dst[C][R] = src[R][C]^T.
__global__ __launch_bounds__(256) void transpose3(
    const float* __restrict__ s0, ushort_t* __restrict__ d0,
    const float* __restrict__ s1, ushort_t* __restrict__ d1,
    const float* __restrict__ s2, ushort_t* __restrict__ d2) {
  __shared__ ushort_t tile[32][33];
  const int z = blockIdx.z;
  const float* src = (z == 0) ? s0 : (z == 1) ? s1 : s2;
  ushort_t* dst = (z == 0) ? d0 : (z == 1) ? d1 : d2;
  const int R = (z == 2) ? 1024 : 512;
  const int C = (z == 1) ? 1024 : 512;
  const int bx = blockIdx.x * 32;
  const int by = blockIdx.y * 32;
  if (bx >= C || by >= R) return;
  const int tx = threadIdx.x, ty = threadIdx.y;
#pragma unroll
  for (int i = 0; i < 32; i += 8)
    tile[ty + i][tx] = f2bf(src[(size_t)(by + ty + i) * C + (bx + tx)]);
  __syncthreads();
#pragma unroll
  for (int i = 0; i < 32; i += 8)
    dst[(size_t)(bx + ty + i) * R + (by + tx)] = tile[tx][ty + i];
}

// c0[j] = sum_c bv[c]*Wo[c][j] + bo[j].
__global__ __launch_bounds__(256) void c0_kernel(const float* __restrict__ bv,
                                                 const float* __restrict__ Wo,
                                                 const float* __restrict__ bo,
                                                 float* __restrict__ c0) {
  __shared__ float red[8][32];
  const int jl = threadIdx.x & 31;
  const int chunk = threadIdx.x >> 5;
  const int j = blockIdx.x * 32 + jl;
  const int cbase = chunk * 64;
  float s = 0.f;
#pragma unroll 8
  for (int c = 0; c < 64; ++c) s += bv[cbase + c] * Wo[(size_t)(cbase + c) * 512 + j];
  red[chunk][jl] = s;
  __syncthreads();
  if (chunk == 0) {
    float t = bo[j];
#pragma unroll
    for (int q = 0; q < 8; ++q) t += red[q][jl];
    c0[j] = t;
  }
}

// out = LN(p0 [+ p1] + cb + res) * g + b over rows of 512; one wave per row.
template <int RES_F32, int OUT_F32, int TWO_P>
__global__ __launch_bounds__(256) void ln_fused(const float* __restrict__ p0,
                                                const float* __restrict__ p1,
                                                const float* __restrict__ cb,
                                                const void* __restrict__ res_,
                                                const float* __restrict__ g,
                                                const float* __restrict__ b,
                                                void* __restrict__ out_) {
  const int row = blockIdx.x * 4 + (threadIdx.x >> 6);
  const int lane = threadIdx.x & 63;
  const size_t base = (size_t)row * 512 + lane * 8;
  const int col = lane * 8;
  float4 a0 = *(const float4*)(p0 + base);
  float4 a1 = *(const float4*)(p0 + base + 4);
  float4 d0 = *(const float4*)(cb + col);
  float4 d1 = *(const float4*)(cb + col + 4);
  float t[8];
  t[0] = a0.x + d0.x; t[1] = a0.y + d0.y;
  t[2] = a0.z + d0.z; t[3] = a0.w + d0.w;
  t[4] = a1.x + d1.x; t[5] = a1.y + d1.y;
  t[6] = a1.z + d1.z; t[7] = a1.w + d1.w;
  if (TWO_P) {
    float4 c0v = *(const float4*)(p1 + base);
    float4 c1v = *(const float4*)(p1 + base + 4);
    t[0] += c0v.x; t[1] += c0v.y; t[2] += c0v.z; t[3] += c0v.w;
    t[4] += c1v.x; t[5] += c1v.y; t[6] += c1v.z; t[7] += c1v.w;
  }
  float r[8];
  if (RES_F32) {
    const float* res = (const float*)res_;
    float4 e0 = *(const float4*)(res + base);
    float4 e1 = *(const float4*)(res + base + 4);
    r[0] = e0.x; r[1] = e0.y; r[2] = e0.z; r[3] = e0.w;
    r[4] = e1.x; r[5] = e1.y; r[6] = e1.z; r[7] = e1.w;
  } else {
    const ushort_t* res = (const ushort_t*)res_;
    uint4 rv = *(const uint4*)(res + base);
    const ushort_t* rp = (const ushort_t*)&rv;
#pragma unroll
    for (int k = 0; k < 8; ++k) r[k] = bf2f(rp[k]);
  }
  float x[8];
  float s = 0.f, sq = 0.f;
#pragma unroll
  for (int k = 0; k < 8; ++k) {
    float v = t[k] + r[k];
    x[k] = v; s += v; sq += v * v;
  }
#pragma unroll
  for (int off = 32; off > 0; off >>= 1) {
    s += __shfl_xor(s, off);
    sq += __shfl_xor(sq, off);
  }
  const float mean = s * (1.0f / 512.0f);
  const float var = sq * (1.0f / 512.0f) - mean * mean;
  const float rstd = rsqrtf(var + 1e-5f);
  float4 gv0 = *(const float4*)(g + col);
  float4 gv1 = *(const float4*)(g + col + 4);
  float4 bv0 = *(const float4*)(b + col);
  float4 bv1 = *(const float4*)(b + col + 4);
  const float gg[8] = {gv0.x, gv0.y, gv0.z, gv0.w, gv1.x, gv1.y, gv1.z, gv1.w};
  const float bb[8] = {bv0.x, bv0.y, bv0.z, bv0.w, bv1.x, bv1.y, bv1.z, bv1.w};
  float y[8];
#pragma unroll
  for (int k = 0; k < 8; ++k) y[k] = (x[k] - mean) * rstd * gg[k] + bb[k];
  if (OUT_F32) {
    float* out = (float*)out_;
    *(float4*)(out + base) = make_float4(y[0], y[1], y[2], y[3]);
    *(float4*)(out + base + 4) = make_float4(y[4], y[5], y[6], y[7]);
  } else {
    ushort_t* out = (ushort_t*)out_;
    uint4 ov; ushort_t* op = (ushort_t*)&ov;
#pragma unroll
    for (int k = 0; k < 8; ++k) op[k] = f2bf(y[k]);
    *(uint4*)(out + base) = ov;
  }
}

extern "C" void kernel_launch(void* const* d_in, const int* in_sizes, int n_in,
                              void* d_out, int out_size, void* d_ws, size_t ws_size,
                              hipStream_t stream) {
  const float* h_g  = (const float*)d_in[0];
  const float* h_s  = (const float*)d_in[1];
  // d_in[2..5] = Wq,bq,Wk,bk — dead code (softmax over 1 key == 1, attn == V)
  const float* Wv   = (const float*)d_in[6];
  const float* bv   = (const float*)d_in[7];
  const float* Wo   = (const float*)d_in[8];
  const float* bo   = (const float*)d_in[9];
  const float* ln1g = (const float*)d_in[10];
  const float* ln1b = (const float*)d_in[11];
  const float* W1   = (const float*)d_in[12];
  const float* b1   = (const float*)d_in[13];
  const float* W2   = (const float*)d_in[14];
  const float* b2   = (const float*)d_in[15];
  const float* ln2g = (const float*)d_in[16];
  const float* ln2b = (const float*)d_in[17];

  char* ws = (char*)d_ws;
  ushort_t* WoT = (ushort_t*)(ws + 0);            // 512x512 bf16   (0.5 MiB)
  ushort_t* W1T = (ushort_t*)(ws + 524288);       // 1024x512 bf16  (1 MiB)
  ushort_t* W2T = (ushort_t*)(ws + 1572864);      // 512x1024 bf16  (1 MiB)
  ushort_t* Wvp = (ushort_t*)(ws + 2621440);      // 3072x512 bf16  (3 MiB)
  ushort_t* WcT = (ushort_t*)(ws + 5767168);      // 512x3072 bf16  (3 MiB)
  float*    c0f = (float*)(ws + 8912896);         // 512 f32
  float*    p0  = (float*)(ws + 16777216);        // 16384x512 f32  (32 MiB)
  float*    p1  = (float*)(ws + 50331648);        // 16384x512 f32  (32 MiB)
  ushort_t* x   = (ushort_t*)(ws + 83886080);     // 16384x512 bf16 (16 MiB)
  ushort_t* u   = (ushort_t*)(ws + 100663296);    // 16384x1024 bf16 (32 MiB)
  // q0/q1 (W2 partials) alias p0/p1 — p* are dead after LN1.
  float*    q0  = p0;
  float*    q1  = p1;
  (void)in_sizes; (void)n_in; (void)out_size; (void)ws_size;

  // --- prep (tiny) ---
  hipLaunchKernelGGL(permute_wv, dim3(768), dim3(256), 0, stream, Wv, Wvp);
  hipLaunchKernelGGL(transpose3, dim3(32, 32, 3), dim3(32, 8), 0, stream,
                     Wo, WoT, W1, W1T, W2, W2T);
  hipLaunchKernelGGL(c0_kernel, dim3(16), dim3(256), 0, stream, bv, Wo, bo, c0f);

  // --- folded weight: WcT[j][s] = sum_c WoT[j][c] * Wvp[s][c]  (M=512,N=3072,K=512)
  hipLaunchKernelGGL((gemm_bt<0, 0>), dim3(24, 4, 1), dim3(256), 0, stream,
                     WoT, Wvp, (void*)WcT, (const float*)nullptr, 512, 3072, 512, 512);
  // --- p0 = h_s @ Wc  (M=16384,N=512,K=3072) — 8-phase, no split-K
  hipLaunchKernelGGL(gemm8_a32, dim3(2, 128, 1), dim3(512), 131072, stream,
                     h_s, WcT, p0, BB, 512, 3072);
  // --- x = LN1(p0 + c0 + h_g)   (res fp32, out bf16, single partial)
  hipLaunchKernelGGL((ln_fused<1, 0, 0>), dim3(4096), dim3(256), 0, stream,
                     p0, (const float*)nullptr, c0f, (const void*)h_g,
                     ln1g, ln1b, (void*)x);
  // --- u = gelu(x @ W1 + b1)   (M=16384,N=1024,K=512)
  hipLaunchKernelGGL((gemm_bt<1, 1>), dim3(8, 128, 1), dim3(256), 0, stream,
                     x, W1T, (void*)u, b1, BB, 1024, 512, 512);
  // --- q0,q1 = split-K partials of u @ W2   (M=16384,N=512,K=1024, ks=2)
  hipLaunchKernelGGL((gemm_bt<2, 1>), dim3(4, 128, 2), dim3(256), 0, stream,
                     u, W2T, (void*)q0, (const float*)nullptr, BB, 512, 1024, 512);
  // --- out = LN2(q0 + q1 + b2 + x)   (res bf16, out fp32)
  hipLaunchKernelGGL((ln_fused<0, 1, 1>), dim3(4096), dim3(256), 0, stream,
                     q0, q1, b2, (const void*)x, ln2g, ln2b, d_out);
}